// Round 1
// baseline (147.140 us; speedup 1.0000x reference)
//
#include <hip/hip_runtime.h>

// Chamfer loss, N=4, P1=P2=8192, D=3, K=1.
// Fused both-directions min kernel (grid.z=2) + segment-partial reduce.
constexpr int N = 4;
constexpr int P = 8192;          // P1 == P2
constexpr int D = 3;
constexpr int TILE = 256;        // LDS column tile (points)
constexpr int MI = 4;            // rows per thread
constexpr int ROWS_PER_BLOCK = 256 * MI;   // 1024

__global__ __launch_bounds__(256) void chamfer_min_kernel(
    const float* __restrict__ pred, const float* __restrict__ targ,
    const int* __restrict__ lens,
    float* __restrict__ wsA, float* __restrict__ wsB, int seglen)
{
    const bool xtoy = (blockIdx.z == 0);
    const float* __restrict__ rows = xtoy ? pred : targ;
    const float* __restrict__ cols = xtoy ? targ : pred;
    float* partial = xtoy ? wsA : wsB;
    const int nseg = gridDim.y;

    const int b    = blockIdx.x >> 3;      // P / ROWS_PER_BLOCK == 8 blocks-of-rows
    const int rt   = blockIdx.x & 7;
    const int row0 = rt * ROWS_PER_BLOCK;
    const int seg  = blockIdx.y;
    const int c0   = seg * seglen;
    const int L    = lens[b];
    const int tid  = threadIdx.x;

    float* pout = partial + ((size_t)b * nseg + seg) * P;

    if (xtoy) {
        if (c0 >= L) {
            // no valid columns in this segment: min is +inf. Must write (ws is
            // poisoned to 0xAA == negative float before every timed call).
            #pragma unroll
            for (int k = 0; k < MI; ++k) pout[row0 + tid + k * 256] = 1e30f;
            return;
        }
    } else {
        if (row0 >= L) return;             // padded target rows: outputs never read
    }

    const float* rbase = rows + (size_t)b * P * D;
    const float* cbase = cols + (size_t)b * P * D;

    float rx[MI], ry[MI], rz[MI], best[MI];
    #pragma unroll
    for (int k = 0; k < MI; ++k) {
        const float* p = rbase + (size_t)(row0 + tid + k * 256) * D;
        rx[k] = p[0]; ry[k] = p[1]; rz[k] = p[2];
        best[k] = 1e30f;
    }

    __shared__ float4 sy[TILE];

    for (int t0 = c0; t0 < c0 + seglen; t0 += TILE) {
        const int idx = t0 + tid;
        float cx, cy, cz;
        if (xtoy && idx >= L) {
            cx = cy = cz = 1e18f;          // d2 ~ 3e36, never selected as min
        } else {
            const float* p = cbase + (size_t)idx * D;
            cx = p[0]; cy = p[1]; cz = p[2];
        }
        __syncthreads();                   // previous tile's readers done
        sy[tid] = make_float4(cx, cy, cz, 0.f);
        __syncthreads();                   // tile visible to all

        #pragma unroll 4
        for (int jj = 0; jj < TILE; ++jj) {
            float4 q = sy[jj];             // ds_read_b128, wave-uniform broadcast
            #pragma unroll
            for (int k = 0; k < MI; ++k) {
                float dx = rx[k] - q.x;
                float dy = ry[k] - q.y;
                float dz = rz[k] - q.z;
                float d2 = dx * dx + dy * dy + dz * dz;
                best[k] = fminf(best[k], d2);
            }
        }
    }

    #pragma unroll
    for (int k = 0; k < MI; ++k) pout[row0 + tid + k * 256] = best[k];
}

__global__ __launch_bounds__(256) void chamfer_reduce_kernel(
    const float* __restrict__ wsA, const float* __restrict__ wsB,
    const int* __restrict__ lens, float* __restrict__ out, int nseg)
{
    const int item = blockIdx.x * 256 + threadIdx.x;   // 2*N*P items
    const int dir  = item >> 15;                       // / (N*P)
    const int rem  = item & (N * P - 1);
    const int b    = rem >> 13;                        // / P
    const int p    = rem & (P - 1);
    const int L    = lens[b];

    float c = 0.f;
    if (dir == 0 || p < L) {
        const float* base = (dir ? wsB : wsA) + (size_t)b * nseg * P + p;
        float v = 1e30f;
        for (int s = 0; s < nseg; ++s) v = fminf(v, base[(size_t)s * P]);
        c = dir ? v / ((float)L * (float)N)
                : v * (1.0f / ((float)P * (float)N));
    }

    // block sum -> one atomicAdd per block
    for (int off = 32; off; off >>= 1) c += __shfl_down(c, off, 64);
    __shared__ float acc[4];
    const int lane = threadIdx.x & 63, wv = threadIdx.x >> 6;
    if (lane == 0) acc[wv] = c;
    __syncthreads();
    if (threadIdx.x == 0) atomicAdd(out, acc[0] + acc[1] + acc[2] + acc[3]);
}

extern "C" void kernel_launch(void* const* d_in, const int* in_sizes, int n_in,
                              void* d_out, int out_size, void* d_ws, size_t ws_size,
                              hipStream_t stream)
{
    const float* pred = (const float*)d_in[0];
    const float* targ = (const float*)d_in[1];
    const int*   lens = (const int*)d_in[2];
    float* out = (float*)d_out;

    // pick segment count from available workspace: need 2*N*nseg*P floats
    int nseg;
    const size_t need32 = (size_t)2 * N * 32 * P * sizeof(float);   // 8 MB
    if (ws_size >= need32)          nseg = 32;
    else if (ws_size >= need32 / 2) nseg = 16;
    else                            nseg = 8;
    const int seglen = P / nseg;

    float* wsA = (float*)d_ws;
    float* wsB = wsA + (size_t)N * nseg * P;

    hipMemsetAsync(d_out, 0, sizeof(float), stream);

    dim3 grid(N * (P / ROWS_PER_BLOCK), nseg, 2);
    chamfer_min_kernel<<<grid, 256, 0, stream>>>(pred, targ, lens, wsA, wsB, seglen);
    chamfer_reduce_kernel<<<(2 * N * P) / 256, 256, 0, stream>>>(wsA, wsB, lens, out, nseg);
}

// Round 2
// 111.430 us; speedup vs baseline: 1.3205x; 1.3205x over previous
//
#include <hip/hip_runtime.h>

// Chamfer loss, N=4, P1=P2=8192, D=3, K=1. Single fused kernel.
// d2 = |x|^2 + |y|^2 - 2 x.y. Per column store (-2y, |y|^2); per pair 3 fma + 1 min
// accumulating d2' = d2 - |x|^2; add |x|^2 back per row at the end, clamp >= 0.
constexpr int N = 4;
constexpr int P = 8192;            // P1 == P2
constexpr int TILE = 256;          // columns staged in LDS per iteration
constexpr int MI = 4;              // rows per thread
constexpr int CHUNKS = 8;          // threads covering a row (column split)
constexpr int RT = 32;             // row tiles per block
constexpr int ROWS = RT * MI;      // 128 rows per block
constexpr int BLK_PER_B = P / ROWS;// 64

__global__ __launch_bounds__(256) void chamfer_fused_kernel(
    const float* __restrict__ pred, const float* __restrict__ targ,
    const int* __restrict__ lens, float* __restrict__ out)
{
    const bool xtoy = (blockIdx.z == 0);
    const int b    = blockIdx.x / BLK_PER_B;
    const int rt   = blockIdx.x % BLK_PER_B;
    const int row0 = rt * ROWS;
    const int L    = lens[b];
    const int tid  = threadIdx.x;
    const int chunk   = tid >> 5;   // 0..7  (wave = 2 chunks -> 2 LDS addrs, free)
    const int rowtile = tid & 31;   // 0..31

    if (!xtoy && row0 >= L) return;          // padded target rows: contribute 0

    const float* rows = xtoy ? pred : targ;  // the side we take min FOR
    const float* cols = xtoy ? targ : pred;  // the side we min OVER
    const float* rbase = rows + (size_t)b * P * 3;
    const float* cbase = cols + (size_t)b * P * 3;

    __shared__ float4 sy[TILE];              // transformed column tile
    __shared__ float  sx2[ROWS];             // |x|^2 per row
    __shared__ float  red[ROWS * CHUNKS];    // min-reduction scratch
    __shared__ float  acc[4];

    float rx[MI], ry[MI], rz[MI], best[MI];
    #pragma unroll
    for (int k = 0; k < MI; ++k) {
        const int r = rowtile * MI + k;
        const float* p = rbase + (size_t)(row0 + r) * 3;
        rx[k] = p[0]; ry[k] = p[1]; rz[k] = p[2];
        best[k] = 1e30f;
        if (chunk == 0)
            sx2[r] = rx[k]*rx[k] + ry[k]*ry[k] + rz[k]*rz[k];
    }

    // x->y only needs tiles that contain valid columns (L >= P/2 always)
    const int ntiles = xtoy ? (L + TILE - 1) / TILE : P / TILE;

    for (int t = 0; t < ntiles; ++t) {
        const int col = t * TILE + tid;
        float4 cv;
        if (xtoy && col >= L) {
            cv = make_float4(0.f, 0.f, 0.f, 1e30f);   // d2' = 1e30, never wins
        } else {
            const float* p = cbase + (size_t)col * 3;
            const float a = p[0], bb = p[1], cc = p[2];
            cv = make_float4(-2.f*a, -2.f*bb, -2.f*cc, a*a + bb*bb + cc*cc);
        }
        __syncthreads();                      // previous tile's readers done
        sy[tid] = cv;
        __syncthreads();

        const float4* sp = &sy[chunk * 32];
        #pragma unroll 8
        for (int jj = 0; jj < 32; ++jj) {
            const float4 q = sp[jj];          // broadcast within half-wave
            #pragma unroll
            for (int k = 0; k < MI; ++k) {
                float d = fmaf(rz[k], q.z, q.w);
                d = fmaf(ry[k], q.y, d);
                d = fmaf(rx[k], q.x, d);      // d = |y|^2 - 2 x.y = d2 - |x|^2
                best[k] = fminf(best[k], d);
            }
        }
    }

    // 8-way min across chunks per row, then scale + block-sum + one atomicAdd
    #pragma unroll
    for (int k = 0; k < MI; ++k)
        red[(rowtile * MI + k) * CHUNKS + chunk] = best[k];
    __syncthreads();

    float c = 0.f;
    if (tid < ROWS) {
        float v = red[tid * CHUNKS];
        #pragma unroll
        for (int i = 1; i < CHUNKS; ++i) v = fminf(v, red[tid * CHUNKS + i]);
        const float d2 = fmaxf(v + sx2[tid], 0.f);
        if (xtoy)                 c = d2 * (1.0f / ((float)P * (float)N));
        else if (row0 + tid < L)  c = d2 / ((float)L * (float)N);
    }
    #pragma unroll
    for (int off = 32; off; off >>= 1) c += __shfl_down(c, off, 64);
    if ((tid & 63) == 0) acc[tid >> 6] = c;
    __syncthreads();
    if (tid == 0) atomicAdd(out, acc[0] + acc[1] + acc[2] + acc[3]);
}

extern "C" void kernel_launch(void* const* d_in, const int* in_sizes, int n_in,
                              void* d_out, int out_size, void* d_ws, size_t ws_size,
                              hipStream_t stream)
{
    const float* pred = (const float*)d_in[0];
    const float* targ = (const float*)d_in[1];
    const int*   lens = (const int*)d_in[2];
    float* out = (float*)d_out;

    hipMemsetAsync(out, 0, out_size * sizeof(float), stream);
    dim3 grid(N * BLK_PER_B, 1, 2);          // 512 blocks
    chamfer_fused_kernel<<<grid, 256, 0, stream>>>(pred, targ, lens, out);
}

// Round 3
// 107.617 us; speedup vs baseline: 1.3673x; 1.0354x over previous
//
#include <hip/hip_runtime.h>

// Chamfer loss, N=4, P1=P2=8192, D=3, K=1.
// Main kernel: per (dir, batch, 512-row group, 1024-col segment) block,
// d2' = |col|^2 - 2 row.col accumulated as 3 fma + min3 per 2 cols,
// MI=16 rows/thread so one ds_read_b128 serves 1024 pair-ops.
// Writes min_cols(d2') + |row|^2 per row to ws; reduce kernel does
// min-over-segments, clamp, scale, sum, atomicAdd.
constexpr int N = 4;
constexpr int P = 8192;
constexpr int NSEG = 8;
constexpr int SEGC = P / NSEG;      // 1024 cols per segment
constexpr int TILE = 256;           // cols staged in LDS per iter
constexpr int ROWS = 512;           // rows per block
constexpr int MI = 16;              // rows per thread
constexpr int RGROUPS = P / ROWS;   // 16
// ws: [dir][b][seg][P] floats = 2*4*8*8192 = 512K floats (2 MB)

__global__ __launch_bounds__(256, 4) void chamfer_min_kernel(
    const float* __restrict__ pred, const float* __restrict__ targ,
    const int* __restrict__ lens, float* __restrict__ ws)
{
    int id = blockIdx.x;
    const int seg = id & (NSEG - 1);    id /= NSEG;
    const int rg  = id & (RGROUPS - 1); id /= RGROUPS;
    const int b   = id & (N - 1);       id /= N;
    const int dir = id;                  // 0: pred rows->targ cols, 1: reverse
    const int row0 = rg * ROWS;
    const int c0   = seg * SEGC;
    const int L    = lens[b];
    const int tid  = threadIdx.x;
    const int chunk   = tid >> 5;        // 0..7: 32-col slice of the tile
    const int rowtile = tid & 31;

    float* slot = ws + (((size_t)dir * N + b) * NSEG + seg) * P + row0;

    if (dir == 1 && row0 >= L) return;           // rows invalid: never read
    if (dir == 0 && c0 >= L) {                   // cols invalid: sentinel
        reinterpret_cast<float2*>(slot)[tid] = make_float2(1e30f, 1e30f);
        return;
    }

    const float* rbase = (dir == 0 ? pred : targ) + (size_t)b * P * 3;
    const float* cbase = (dir == 0 ? targ : pred) + (size_t)b * P * 3;

    float rx[MI], ry[MI], rz[MI], best[MI];
    #pragma unroll
    for (int k = 0; k < MI; ++k) {
        const float* p = rbase + (size_t)(row0 + rowtile + 32 * k) * 3;
        rx[k] = p[0]; ry[k] = p[1]; rz[k] = p[2];
        best[k] = 1e30f;
    }

    __shared__ float4 sy[TILE];
    __shared__ float  red[ROWS * 9];     // 8 chunk-mins + |row|^2, stride 9

    int vc = SEGC;                        // valid cols in this segment
    if (dir == 0 && L - c0 < SEGC) vc = L - c0;
    const int nt = (vc + TILE - 1) / TILE;

    for (int t = 0; t < nt; ++t) {
        const int col = c0 + t * TILE + tid;
        float4 cv;
        if (dir == 0 && col >= L) {
            cv = make_float4(0.f, 0.f, 0.f, 1e30f);      // never wins the min
        } else {
            const float* p = cbase + (size_t)col * 3;
            const float a = p[0], bb = p[1], cc = p[2];
            cv = make_float4(-2.f*a, -2.f*bb, -2.f*cc, a*a + bb*bb + cc*cc);
        }
        __syncthreads();
        sy[tid] = cv;
        __syncthreads();

        const float4* sp = &sy[chunk * 32];
        #pragma unroll 2
        for (int jj = 0; jj < 32; jj += 2) {
            const float4 q0 = sp[jj];
            const float4 q1 = sp[jj + 1];
            #pragma unroll
            for (int k = 0; k < MI; ++k) {
                float d0 = fmaf(rx[k], q0.x, fmaf(ry[k], q0.y, fmaf(rz[k], q0.z, q0.w)));
                float d1 = fmaf(rx[k], q1.x, fmaf(ry[k], q1.y, fmaf(rz[k], q1.z, q1.w)));
                best[k] = fminf(best[k], fminf(d0, d1));  // -> v_min3_f32
            }
        }
    }

    #pragma unroll
    for (int k = 0; k < MI; ++k)
        red[(rowtile + 32 * k) * 9 + chunk] = best[k];   // stride 9: no conflicts
    if (chunk == 0) {
        #pragma unroll
        for (int k = 0; k < MI; ++k)
            red[(rowtile + 32 * k) * 9 + 8] =
                fmaf(rx[k], rx[k], fmaf(ry[k], ry[k], rz[k] * rz[k]));
    }
    __syncthreads();

    // two rows per thread -> one float2 store
    {
        const float* r0 = &red[(tid * 2) * 9];
        const float* r1 = &red[(tid * 2 + 1) * 9];
        float v0 = fminf(fminf(fminf(r0[0], r0[1]), fminf(r0[2], r0[3])),
                         fminf(fminf(r0[4], r0[5]), fminf(r0[6], r0[7]))) + r0[8];
        float v1 = fminf(fminf(fminf(r1[0], r1[1]), fminf(r1[2], r1[3])),
                         fminf(fminf(r1[4], r1[5]), fminf(r1[6], r1[7]))) + r1[8];
        reinterpret_cast<float2*>(slot)[tid] = make_float2(v0, v1);
    }
}

__global__ __launch_bounds__(256) void chamfer_reduce_kernel(
    const float* __restrict__ ws, const int* __restrict__ lens,
    float* __restrict__ out)
{
    const int item = blockIdx.x * 256 + threadIdx.x;     // 2*N*P = 65536
    const int dir = item >> 15;
    const int b   = (item >> 13) & (N - 1);
    const int p   = item & (P - 1);
    const int L   = lens[b];

    float c = 0.f;
    if (dir == 0 || p < L) {
        const float* base = ws + (((size_t)dir * N + b) * NSEG) * P + p;
        float v = base[0];
        #pragma unroll
        for (int s = 1; s < NSEG; ++s) v = fminf(v, base[(size_t)s * P]);
        v = fmaxf(v, 0.f);
        c = dir ? v / ((float)L * (float)N) : v * (1.0f / ((float)P * (float)N));
    }
    #pragma unroll
    for (int off = 32; off; off >>= 1) c += __shfl_down(c, off, 64);
    __shared__ float acc[4];
    if ((threadIdx.x & 63) == 0) acc[threadIdx.x >> 6] = c;
    __syncthreads();
    if (threadIdx.x == 0) atomicAdd(out, acc[0] + acc[1] + acc[2] + acc[3]);
}

extern "C" void kernel_launch(void* const* d_in, const int* in_sizes, int n_in,
                              void* d_out, int out_size, void* d_ws, size_t ws_size,
                              hipStream_t stream)
{
    const float* pred = (const float*)d_in[0];
    const float* targ = (const float*)d_in[1];
    const int*   lens = (const int*)d_in[2];
    float* out = (float*)d_out;
    float* ws  = (float*)d_ws;      // 2 MB used; every read slot is written

    hipMemsetAsync(out, 0, out_size * sizeof(float), stream);
    const int nblk = 2 * N * RGROUPS * NSEG;            // 1024
    chamfer_min_kernel<<<nblk, 256, 0, stream>>>(pred, targ, lens, ws);
    chamfer_reduce_kernel<<<(2 * N * P) / 256, 256, 0, stream>>>(ws, lens, out);
}

// Round 4
// 105.179 us; speedup vs baseline: 1.3990x; 1.0232x over previous
//
#include <hip/hip_runtime.h>

// Chamfer loss, N=4, P1=P2=8192, D=3, K=1.
// Main kernel: block = (dir, batch, 256-row group, col segment).
// Rows in VGPRs (MI=8/thread -> low pressure, no AGPR shuffling),
// columns staged per 256-tile in LDS as (-2x,-2y,-2z,|y|^2),
// per pair 3 fma + shared min3 accumulating d2' = d2 - |row|^2.
// Per-row (min over segment cols) + |row|^2 written to ws;
// reduce kernel: min over segments, clamp, scale, block-sum, atomicAdd.
constexpr int N = 4;
constexpr int P = 8192;
constexpr int TILE = 256;          // cols staged in LDS per iter
constexpr int MI = 8;              // rows per thread
constexpr int ROWS = 256;          // rows per block (32 rowtiles * MI)
constexpr int RG = P / ROWS;       // 32 row groups per (dir,b)

__global__ __launch_bounds__(256) void chamfer_min_kernel(
    const float* __restrict__ pred, const float* __restrict__ targ,
    const int* __restrict__ lens, float* __restrict__ ws)
{
    const int nseg = gridDim.y;
    const int segc = P / nseg;
    const int seg  = blockIdx.y;
    int id = blockIdx.x;                    // 2*N*RG = 256
    const int rg  = id & (RG - 1); id >>= 5;
    const int b   = id & (N - 1);  id >>= 2;
    const int dir = id;                     // 0: pred rows / targ cols
    const int row0 = rg * ROWS;
    const int c0   = seg * segc;
    const int L    = lens[b];
    const int tid  = threadIdx.x;
    const int chunk   = tid >> 5;           // 0..7: 32-col slice of tile
    const int rowtile = tid & 31;

    float* slot = ws + (((size_t)dir * N + b) * nseg + seg) * P + row0;

    if (dir == 1 && row0 >= L) return;      // padded target rows: never read
    if (dir == 0 && c0 >= L) {              // no valid cols here: sentinel
        slot[tid] = 1e30f;
        return;
    }

    const float* rbase = (dir == 0 ? pred : targ) + (size_t)b * P * 3;
    const float* cbase = (dir == 0 ? targ : pred) + (size_t)b * P * 3;

    float rx[MI], ry[MI], rz[MI], best[MI];
    #pragma unroll
    for (int k = 0; k < MI; ++k) {
        const float* p = rbase + (size_t)(row0 + rowtile + 32 * k) * 3;
        rx[k] = p[0]; ry[k] = p[1]; rz[k] = p[2];
        best[k] = 1e30f;
    }

    __shared__ float4 sy[TILE];
    __shared__ float  red[ROWS * 9];        // 8 chunk-mins + |row|^2, stride 9

    int vc = segc;                          // valid cols in this segment
    if (dir == 0 && L - c0 < segc) vc = L - c0;
    const int nt = (vc + TILE - 1) / TILE;

    for (int t = 0; t < nt; ++t) {
        const int col = c0 + t * TILE + tid;
        float4 cv;
        if (dir == 0 && col >= L) {
            cv = make_float4(0.f, 0.f, 0.f, 1e30f);   // never wins the min
        } else {
            const float* p = cbase + (size_t)col * 3;
            const float a = p[0], bb = p[1], cc = p[2];
            cv = make_float4(-2.f*a, -2.f*bb, -2.f*cc, a*a + bb*bb + cc*cc);
        }
        __syncthreads();
        sy[tid] = cv;
        __syncthreads();

        const float4* sp = &sy[chunk * 32];
        #pragma unroll 4
        for (int jj = 0; jj < 32; jj += 2) {
            const float4 q0 = sp[jj];
            const float4 q1 = sp[jj + 1];
            #pragma unroll
            for (int k = 0; k < MI; ++k) {
                float d0 = fmaf(rx[k], q0.x, fmaf(ry[k], q0.y, fmaf(rz[k], q0.z, q0.w)));
                float d1 = fmaf(rx[k], q1.x, fmaf(ry[k], q1.y, fmaf(rz[k], q1.z, q1.w)));
                best[k] = fminf(best[k], fminf(d0, d1));   // -> v_min3_f32
            }
        }
    }

    #pragma unroll
    for (int k = 0; k < MI; ++k)
        red[(rowtile + 32 * k) * 9 + chunk] = best[k];
    if (chunk == 0) {
        #pragma unroll
        for (int k = 0; k < MI; ++k)
            red[(rowtile + 32 * k) * 9 + 8] =
                fmaf(rx[k], rx[k], fmaf(ry[k], ry[k], rz[k] * rz[k]));
    }
    __syncthreads();

    {   // one row per thread: 8-way min + |row|^2, store to ws
        const float* r = &red[tid * 9];
        float v = fminf(fminf(fminf(r[0], r[1]), fminf(r[2], r[3])),
                        fminf(fminf(r[4], r[5]), fminf(r[6], r[7])));
        slot[tid] = v + r[8];
    }
}

__global__ __launch_bounds__(256) void chamfer_reduce_kernel(
    const float* __restrict__ ws, const int* __restrict__ lens,
    float* __restrict__ out, int nseg)
{
    const int item = blockIdx.x * 256 + threadIdx.x;     // 2*N*P = 65536
    const int dir = item >> 15;
    const int b   = (item >> 13) & (N - 1);
    const int p   = item & (P - 1);
    const int L   = lens[b];

    float c = 0.f;
    if (dir == 0 || p < L) {
        const float* base = ws + (((size_t)dir * N + b) * nseg) * P + p;
        float v = base[0];
        for (int s = 1; s < nseg; ++s) v = fminf(v, base[(size_t)s * P]);
        v = fmaxf(v, 0.f);
        c = dir ? v / ((float)L * (float)N) : v * (1.0f / ((float)P * (float)N));
    }
    #pragma unroll
    for (int off = 32; off; off >>= 1) c += __shfl_down(c, off, 64);
    __shared__ float acc[4];
    if ((threadIdx.x & 63) == 0) acc[threadIdx.x >> 6] = c;
    __syncthreads();
    if (threadIdx.x == 0) atomicAdd(out, acc[0] + acc[1] + acc[2] + acc[3]);
}

extern "C" void kernel_launch(void* const* d_in, const int* in_sizes, int n_in,
                              void* d_out, int out_size, void* d_ws, size_t ws_size,
                              hipStream_t stream)
{
    const float* pred = (const float*)d_in[0];
    const float* targ = (const float*)d_in[1];
    const int*   lens = (const int*)d_in[2];
    float* out = (float*)d_out;
    float* ws  = (float*)d_ws;

    // ws need: 2*N*nseg*P floats. nseg=16 -> 4 MB, nseg=8 -> 2 MB.
    const int nseg = (ws_size >= (size_t)2 * N * 16 * P * sizeof(float)) ? 16 : 8;

    hipMemsetAsync(out, 0, out_size * sizeof(float), stream);
    dim3 grid(2 * N * RG, nseg);            // 256 * nseg blocks
    chamfer_min_kernel<<<grid, 256, 0, stream>>>(pred, targ, lens, ws);
    chamfer_reduce_kernel<<<(2 * N * P) / 256, 256, 0, stream>>>(ws, lens, out, nseg);
}